// Round 9
// baseline (3456.963 us; speedup 1.0000x reference)
//
#include <hip/hip_runtime.h>
#include <hip/hip_bf16.h>
#include <math.h>

#define D_MODEL 2048
#define D_FFN   8192
#define N_HEADS 16
#define D_HEAD  128
#define BATCH   2
#define SEQ     2048
#define M_TOK   (BATCH*SEQ)          /* 4096 tokens */
#define EPSF    1.1920929e-07f
#define QK_SCALE 0.08838834764831845f /* 1/sqrt(128) */

typedef __attribute__((ext_vector_type(4))) float  f32x4;
typedef __attribute__((ext_vector_type(8))) __bf16 bf16x8;
typedef __attribute__((ext_vector_type(4))) __bf16 bf16x4;

static __device__ __forceinline__ f32x4 mfma_bf16(bf16x8 a, bf16x8 b, f32x4 c) {
    return __builtin_amdgcn_mfma_f32_16x16x32_bf16(a, b, c, 0, 0, 0);
}

// async global->LDS, 16B per lane. LDS dest = wave-uniform base + lane*16.
static __device__ __forceinline__ void gload_lds16(const void* g, void* l) {
    __builtin_amdgcn_global_load_lds(
        (const __attribute__((address_space(1))) void*)g,
        (__attribute__((address_space(3))) void*)l, 16, 0, 0);
}

// ---------------------------------------------------------------------------
// fp32 -> bf16 hi/lo split, vectorized grid-stride. n4 = n/4.
// ---------------------------------------------------------------------------
__global__ __launch_bounds__(256) void split_k(const float* __restrict__ X,
                                               __bf16* __restrict__ H,
                                               __bf16* __restrict__ L, int n4)
{
    int i = blockIdx.x * 256 + threadIdx.x;
    const int stride = gridDim.x * 256;
    for (; i < n4; i += stride) {
        f32x4 v = ((const f32x4*)X)[i];
        bf16x4 h4, l4;
#pragma unroll
        for (int j = 0; j < 4; ++j) {
            __bf16 h = (__bf16)v[j];
            h4[j] = h;
            l4[j] = (__bf16)(v[j] - (float)h);
        }
        ((bf16x4*)H)[i] = h4;
        ((bf16x4*)L)[i] = l4;
    }
}

// ---------------------------------------------------------------------------
// RMSNorm -> bf16 hi/lo. One block per row of 2048. 256 thr * 8 elems.
// ---------------------------------------------------------------------------
__global__ __launch_bounds__(256) void rmsnorm_split_k(const float* __restrict__ X,
                                                       const float* __restrict__ g,
                                                       __bf16* __restrict__ H,
                                                       __bf16* __restrict__ L)
{
    const int row = blockIdx.x;
    const int t   = threadIdx.x;
    const int lane = t & 63;
    const int wid  = t >> 6;
    const float* x = X + (size_t)row * D_MODEL + t * 8;

    f32x4 v0 = *(const f32x4*)(x);
    f32x4 v1 = *(const f32x4*)(x + 4);
    float ss = 0.f;
#pragma unroll
    for (int i = 0; i < 4; ++i) ss += v0[i]*v0[i] + v1[i]*v1[i];
#pragma unroll
    for (int off = 32; off > 0; off >>= 1) ss += __shfl_down(ss, off);

    __shared__ float red[4];
    if (lane == 0) red[wid] = ss;
    __syncthreads();
    float tot = red[0] + red[1] + red[2] + red[3];
    float scale = rsqrtf(tot * (1.0f / D_MODEL) + EPSF);

    f32x4 g0 = *(const f32x4*)(g + t * 8);
    f32x4 g1 = *(const f32x4*)(g + t * 8 + 4);
    bf16x4 h0, l0, h1, l1;
#pragma unroll
    for (int i = 0; i < 4; ++i) {
        float a = v0[i]*scale*g0[i];
        float b = v1[i]*scale*g1[i];
        __bf16 ha = (__bf16)a; h0[i] = ha; l0[i] = (__bf16)(a - (float)ha);
        __bf16 hb = (__bf16)b; h1[i] = hb; l1[i] = (__bf16)(b - (float)hb);
    }
    const size_t o = (size_t)row * D_MODEL + t * 8;
    *(bf16x4*)(H + o)     = h0;
    *(bf16x4*)(H + o + 4) = h1;
    *(bf16x4*)(L + o)     = l0;
    *(bf16x4*)(L + o + 4) = l1;
}

// ---------------------------------------------------------------------------
// GEMM  C[M,N] = (Ah+Al)[M,K] * (Bh+Bl)[N,K]^T  via 3 bf16 MFMAs per frag pair.
// 128x128 tile, BK=32, 4 waves of 64x64, global_load_lds(16B), double-buffered
// LDS with ONE barrier per K-step (prefetch issued after barrier, drained by
// the NEXT barrier -> overlaps MFMA+ds_read of current tile).
// k-chunk XOR swizzle cb^=(row>>1)&3 applied BOTH to the global source chunk
// and the ds_read (rule 21) -> frag reads 2-way = conflict-free.
// Bijective XCD swizzle on flat block id (nwg % 8 == 0 for all our grids).
// EPI: 0 = fp32 C; 1 = fp32 C += Res (C may alias Res); 2 = GELU -> Ch/Cl.
// ---------------------------------------------------------------------------
template<int EPI>
__global__ __launch_bounds__(256, 2) void gemm_hl(const __bf16* __restrict__ Ah,
                                                  const __bf16* __restrict__ Al,
                                                  const __bf16* __restrict__ Bh,
                                                  const __bf16* __restrict__ Bl,
                                                  const float* Res,
                                                  float* C,
                                                  __bf16* Ch,
                                                  __bf16* Cl,
                                                  int M, int N, int K)
{
    __shared__ __bf16 sAh[2][128*32];
    __shared__ __bf16 sAl[2][128*32];
    __shared__ __bf16 sBh[2][128*32];
    __shared__ __bf16 sBl[2][128*32];

    const int tid = threadIdx.x;
    const int w   = tid >> 6;
    const int l   = tid & 63;

    // XCD-aware bijective block swizzle (nwg multiple of 8)
    const int gx  = gridDim.x;
    const int nwg = gx * gridDim.y;
    int flat = blockIdx.y * gx + blockIdx.x;
    flat = (flat & 7) * (nwg >> 3) + (flat >> 3);
    const int bm = (flat / gx) * 128;
    const int bn = (flat % gx) * 128;

    // staging geometry: wave w covers tile rows [w*32, w*32+32), 2 issues/array
    const int r0  = w*32 + (l >> 2);             // q=0 row (0..127)
    const int r1  = r0 + 16;                     // q=1 row
    const int cb0 = (l & 3) ^ ((r0 >> 1) & 3);   // global k-chunk feeding slot
    const int cb1 = (l & 3) ^ ((r1 >> 1) & 3);
    const int off0 = w*1024;                     // LDS element base, q=0
    const int off1 = w*1024 + 512;               // q=1

    const size_t gA0 = (size_t)(bm + r0) * K + cb0*8;
    const size_t gA1 = (size_t)(bm + r1) * K + cb1*8;
    const size_t gB0 = (size_t)(bn + r0) * K + cb0*8;
    const size_t gB1 = (size_t)(bn + r1) * K + cb1*8;

    // compute geometry
    const int wm = (w >> 1) * 64;
    const int wn = (w & 1) * 64;
    const int lr = l & 15;
    const int lk = l >> 4;

    f32x4 acc[4][4] = {};

    auto stage = [&](int buf, int kt) {
        gload_lds16(Ah + gA0 + kt, &sAh[buf][off0]);
        gload_lds16(Ah + gA1 + kt, &sAh[buf][off1]);
        gload_lds16(Al + gA0 + kt, &sAl[buf][off0]);
        gload_lds16(Al + gA1 + kt, &sAl[buf][off1]);
        gload_lds16(Bh + gB0 + kt, &sBh[buf][off0]);
        gload_lds16(Bh + gB1 + kt, &sBh[buf][off1]);
        gload_lds16(Bl + gB0 + kt, &sBl[buf][off0]);
        gload_lds16(Bl + gB1 + kt, &sBl[buf][off1]);
    };

    stage(0, 0);                      // prologue prefetch

    int b = 0;
    for (int kt = 0; kt < K; kt += 32, b ^= 1) {
        __syncthreads();              // drains vmcnt: buf b ready; buf b^1 free
        if (kt + 32 < K) stage(b ^ 1, kt + 32);

        bf16x8 ah[4], al[4], bh[4], bl[4];
#pragma unroll
        for (int i = 0; i < 4; ++i) {
            const int ra = wm + i*16 + lr;
            const int ca = (lk ^ ((ra >> 1) & 3)) * 8;
            ah[i] = *(const bf16x8*)&sAh[b][ra*32 + ca];
            al[i] = *(const bf16x8*)&sAl[b][ra*32 + ca];
            const int rb = wn + i*16 + lr;
            const int cbv = (lk ^ ((rb >> 1) & 3)) * 8;
            bh[i] = *(const bf16x8*)&sBh[b][rb*32 + cbv];
            bl[i] = *(const bf16x8*)&sBl[b][rb*32 + cbv];
        }
#pragma unroll
        for (int i = 0; i < 4; ++i) {
#pragma unroll
            for (int j = 0; j < 4; ++j) {
                acc[i][j] = mfma_bf16(ah[i], bh[j], acc[i][j]);
                acc[i][j] = mfma_bf16(al[i], bh[j], acc[i][j]);
                acc[i][j] = mfma_bf16(ah[i], bl[j], acc[i][j]);
            }
        }
    }

    // C/D frag: col = lane&15 -> n ; row = (lane>>4)*4 + reg -> m  (m89/m91)
#pragma unroll
    for (int i = 0; i < 4; ++i) {
#pragma unroll
        for (int j = 0; j < 4; ++j) {
            const int n  = bn + wn + j*16 + lr;
            const int m0 = bm + wm + i*16 + lk*4;
#pragma unroll
            for (int r = 0; r < 4; ++r) {
                float v = acc[i][j][r];
                const size_t idx = (size_t)(m0 + r) * N + n;
                if (EPI == 0) {
                    C[idx] = v;
                } else if (EPI == 1) {
                    C[idx] = v + Res[idx];
                } else {
                    v = 0.5f * v * (1.0f + erff(v * 0.70710678118654752f));
                    __bf16 h = (__bf16)v;
                    Ch[idx] = h;
                    Cl[idx] = (__bf16)(v - (float)h);
                }
            }
        }
    }
}

// ---------------------------------------------------------------------------
// Flash attention fp32 (causal). Grid (S/32, B*H). 256 thr.
// 32 queries/block; each query owned by 8 lanes; lane owns dims 4*sub + 32*i.
// Output written directly as bf16 hi/lo (feeds the Wo GEMM).
// ---------------------------------------------------------------------------
__global__ __launch_bounds__(256, 2) void flash_attn(const float* __restrict__ Q,
                                                     const float* __restrict__ K,
                                                     const float* __restrict__ V,
                                                     __bf16* __restrict__ OH,
                                                     __bf16* __restrict__ OL)
{
    __shared__ float Kt[32][128];
    __shared__ float Vt[32][128];

    const int qb   = blockIdx.x;
    const int bh   = blockIdx.y;
    const int b    = bh >> 4;
    const int h    = bh & 15;
    const int tid  = threadIdx.x;
    const int w    = tid >> 6;
    const int lane = tid & 63;
    const int g8   = lane >> 3;
    const int sub  = lane & 7;
    const int ql   = w * 8 + g8;          // 0..31
    const int qs   = qb * 32 + ql;        // seq position
    const size_t qoff = ((size_t)(b * SEQ + qs)) * D_MODEL + h * D_HEAD;

    float qr[16];
#pragma unroll
    for (int i = 0; i < 4; ++i) {
        f32x4 v = *(const f32x4*)(Q + qoff + 4*sub + 32*i);
#pragma unroll
        for (int j = 0; j < 4; ++j) qr[4*i + j] = v[j] * QK_SCALE;
    }

    float mx = -1e30f, lsum = 0.f;
    float o[16];
#pragma unroll
    for (int i = 0; i < 16; ++i) o[i] = 0.f;

    const int srow = tid >> 3;            // 0..31
    const int scol = (tid & 7) * 16;      // 0..112
    const int ntiles = qb + 1;

    for (int kt = 0; kt < ntiles; ++kt) {
        __syncthreads();
        const size_t koff = ((size_t)(b * SEQ + kt * 32 + srow)) * D_MODEL + h * D_HEAD + scol;
#pragma unroll
        for (int i = 0; i < 4; ++i) {
            *(f32x4*)&Kt[srow][scol + 4*i] = *(const f32x4*)(K + koff + 4*i);
            *(f32x4*)&Vt[srow][scol + 4*i] = *(const f32x4*)(V + koff + 4*i);
        }
        __syncthreads();

        float sp[32];
#pragma unroll
        for (int kk = 0; kk < 32; ++kk) {
            float p = 0.f;
#pragma unroll
            for (int i = 0; i < 4; ++i) {
                f32x4 kv = *(const f32x4*)&Kt[kk][4*sub + 32*i];
#pragma unroll
                for (int j = 0; j < 4; ++j) p += qr[4*i + j] * kv[j];
            }
            p += __shfl_xor(p, 1, 8);
            p += __shfl_xor(p, 2, 8);
            p += __shfl_xor(p, 4, 8);
            sp[kk] = p;
        }
        if (kt == qb) {
#pragma unroll
            for (int kk = 0; kk < 32; ++kk) if (kk > ql) sp[kk] = -1e30f;
        }
        float tmax = sp[0];
#pragma unroll
        for (int kk = 1; kk < 32; ++kk) tmax = fmaxf(tmax, sp[kk]);
        float mnew = fmaxf(mx, tmax);
        float scl  = __expf(mx - mnew);
        float psum = 0.f;
#pragma unroll
        for (int kk = 0; kk < 32; ++kk) { sp[kk] = __expf(sp[kk] - mnew); psum += sp[kk]; }
        lsum = lsum * scl + psum;
#pragma unroll
        for (int i = 0; i < 16; ++i) o[i] *= scl;
#pragma unroll
        for (int kk = 0; kk < 32; ++kk) {
            float pk = sp[kk];
#pragma unroll
            for (int i = 0; i < 4; ++i) {
                f32x4 vv = *(const f32x4*)&Vt[kk][4*sub + 32*i];
#pragma unroll
                for (int j = 0; j < 4; ++j) o[4*i + j] += pk * vv[j];
            }
        }
        mx = mnew;
    }

    float inv = 1.0f / lsum;
#pragma unroll
    for (int i = 0; i < 4; ++i) {
        bf16x4 h4, l4;
#pragma unroll
        for (int j = 0; j < 4; ++j) {
            float vv = o[4*i + j] * inv;
            __bf16 hh = (__bf16)vv;
            h4[j] = hh;
            l4[j] = (__bf16)(vv - (float)hh);
        }
        *(bf16x4*)(OH + qoff + 4*sub + 32*i) = h4;
        *(bf16x4*)(OL + qoff + 4*sub + 32*i) = l4;
    }
}

// ---------------------------------------------------------------------------
// Tiered launch: pick densest layout that fits ws_size (same branch every
// call -> graph-capture safe). U = MD*2 bytes = 16.78 MB.
//  Tier1 (ws >= 10U = 167.8 MB): CHUNK=2048, all scratch in ws.
//  Tier2 (ws >=  8U = 134.2 MB): CHUNK=1024; Wq/Wk/Wv splits use d_out as
//         scratch (dead until Wo-GEMM writes it); Wo split in dead Qb slot.
//  Tier3: launch nothing -> harness reports clean fail (diagnostic signal).
// ---------------------------------------------------------------------------
extern "C" void kernel_launch(void* const* d_in, const int* in_sizes, int n_in,
                              void* d_out, int out_size, void* d_ws, size_t ws_size,
                              hipStream_t stream)
{
    const float* X      = (const float*)d_in[0];
    // d_in[1] = causal_mask (recomputed analytically, unused)
    const float* g_attn = (const float*)d_in[2];
    const float* g_ffn  = (const float*)d_in[3];
    const float* Wq     = (const float*)d_in[4];
    const float* Wk     = (const float*)d_in[5];
    const float* Wv     = (const float*)d_in[6];
    const float* Wo     = (const float*)d_in[7];
    const float* W1     = (const float*)d_in[8];
    const float* W2     = (const float*)d_in[9];
    float* out = (float*)d_out;

    const size_t DD = (size_t)D_MODEL * D_MODEL;   // 4.19M elements
    const size_t DF = (size_t)D_MODEL * D_FFN;     // 16.78M elements
    const size_t MD = (size_t)M_TOK * D_MODEL;     // 8.39M elements
    const size_t U  = MD * 2;                      // slot unit (bytes)

    char* base = (char*)d_ws;
    dim3 blk(256);

    if (ws_size >= 10 * U) {
        // ================= Tier 1 (round-5 layout, CHUNK=2048) =============
        __bf16* XnH = (__bf16*)(base);
        __bf16* XnL = XnH + MD;
        float*  Qb  = (float*)(base + 2*U);
        float*  Kb  = (float*)(base + 4*U);
        float*  Vb  = (float*)(base + 6*U);
        __bf16* AOH = (__bf16*)(base);
        __bf16* AOL = AOH + MD;
        __bf16* WaH = (__bf16*)(base + 8*U);
        __bf16* WaL = WaH + DD;
        __bf16* hnH = (__bf16*)(base);
        __bf16* hnL = hnH + MD;
        __bf16* GH  = (__bf16*)(base + 2*U);       // 2048 x 8192 hi
        __bf16* GL  = (__bf16*)(base + 4*U);       // 2048 x 8192 lo
        __bf16* WfH = (__bf16*)(base + 6*U);
        __bf16* WfL = (__bf16*)(base + 8*U);

        rmsnorm_split_k<<<M_TOK, blk, 0, stream>>>(X, g_attn, XnH, XnL);

        split_k<<<1024, blk, 0, stream>>>(Wq, WaH, WaL, (int)(DD/4));
        gemm_hl<0><<<dim3(16, 32), blk, 0, stream>>>(XnH, XnL, WaH, WaL, nullptr,
                                                     Qb, nullptr, nullptr, M_TOK, D_MODEL, D_MODEL);
        split_k<<<1024, blk, 0, stream>>>(Wk, WaH, WaL, (int)(DD/4));
        gemm_hl<0><<<dim3(16, 32), blk, 0, stream>>>(XnH, XnL, WaH, WaL, nullptr,
                                                     Kb, nullptr, nullptr, M_TOK, D_MODEL, D_MODEL);
        split_k<<<1024, blk, 0, stream>>>(Wv, WaH, WaL, (int)(DD/4));
        gemm_hl<0><<<dim3(16, 32), blk, 0, stream>>>(XnH, XnL, WaH, WaL, nullptr,
                                                     Vb, nullptr, nullptr, M_TOK, D_MODEL, D_MODEL);

        flash_attn<<<dim3(SEQ/32, BATCH*N_HEADS), blk, 0, stream>>>(Qb, Kb, Vb, AOH, AOL);

        split_k<<<1024, blk, 0, stream>>>(Wo, WaH, WaL, (int)(DD/4));
        gemm_hl<1><<<dim3(16, 32), blk, 0, stream>>>(AOH, AOL, WaH, WaL, X,
                                                     out, nullptr, nullptr, M_TOK, D_MODEL, D_MODEL);

        rmsnorm_split_k<<<M_TOK, blk, 0, stream>>>(out, g_ffn, hnH, hnL);

        for (int c = 0; c < 2; ++c) {
            const size_t roff = (size_t)c * 2048 * D_MODEL;
            split_k<<<2048, blk, 0, stream>>>(W1, WfH, WfL, (int)(DF/4));
            gemm_hl<2><<<dim3(64, 16), blk, 0, stream>>>(
                hnH + roff, hnL + roff, WfH, WfL, nullptr,
                nullptr, GH, GL, 2048, D_FFN, D_MODEL);
            split_k<<<2048, blk, 0, stream>>>(W2, WfH, WfL, (int)(DF/4));
            gemm_hl<1><<<dim3(16, 16), blk, 0, stream>>>(
                GH, GL, WfH, WfL, out + roff,
                out + roff, nullptr, nullptr, 2048, D_MODEL, D_FFN);
        }
    } else if (ws_size >= 8 * U) {
        // ================= Tier 2 (compact, CHUNK=1024) ====================
        __bf16* XnH = (__bf16*)(base);             // [0,2U)
        __bf16* XnL = XnH + MD;
        float*  Qb  = (float*)(base + 2*U);        // [2U,4U)
        float*  Kb  = (float*)(base + 4*U);        // [4U,6U)
        float*  Vb  = (float*)(base + 6*U);        // [6U,8U)
        __bf16* WaH = (__bf16*)d_out;              // d_out as scratch (1U of 2U)
        __bf16* WaL = WaH + DD;
        __bf16* AOH = (__bf16*)(base);             // Xn slot
        __bf16* AOL = AOH + MD;
        __bf16* WoH2= (__bf16*)(base + 2*U);       // Qb slot (dead post-attn)
        __bf16* WoL2= WoH2 + DD;
        __bf16* hnH = (__bf16*)(base);             // AO slot
        __bf16* hnL = hnH + MD;
        __bf16* GH  = (__bf16*)(base + 2*U);       // [2U,3U) 1024 x 8192 hi
        __bf16* GL  = GH + (size_t)1024 * D_FFN;   // [3U,4U)
        __bf16* WfH = (__bf16*)(base + 4*U);       // Kb slot [4U,6U)
        __bf16* WfL = (__bf16*)(base + 6*U);       // Vb slot [6U,8U)

        rmsnorm_split_k<<<M_TOK, blk, 0, stream>>>(X, g_attn, XnH, XnL);

        split_k<<<1024, blk, 0, stream>>>(Wq, WaH, WaL, (int)(DD/4));
        gemm_hl<0><<<dim3(16, 32), blk, 0, stream>>>(XnH, XnL, WaH, WaL, nullptr,
                                                     Qb, nullptr, nullptr, M_TOK, D_MODEL, D_MODEL);
        split_k<<<1024, blk, 0, stream>>>(Wk, WaH, WaL, (int)(DD/4));
        gemm_hl<0><<<dim3(16, 32), blk, 0, stream>>>(XnH, XnL, WaH, WaL, nullptr,
                                                     Kb, nullptr, nullptr, M_TOK, D_MODEL, D_MODEL);
        split_k<<<1024, blk, 0, stream>>>(Wv, WaH, WaL, (int)(DD/4));
        gemm_hl<0><<<dim3(16, 32), blk, 0, stream>>>(XnH, XnL, WaH, WaL, nullptr,
                                                     Vb, nullptr, nullptr, M_TOK, D_MODEL, D_MODEL);

        flash_attn<<<dim3(SEQ/32, BATCH*N_HEADS), blk, 0, stream>>>(Qb, Kb, Vb, AOH, AOL);

        split_k<<<1024, blk, 0, stream>>>(Wo, WoH2, WoL2, (int)(DD/4));
        gemm_hl<1><<<dim3(16, 32), blk, 0, stream>>>(AOH, AOL, WoH2, WoL2, X,
                                                     out, nullptr, nullptr, M_TOK, D_MODEL, D_MODEL);

        rmsnorm_split_k<<<M_TOK, blk, 0, stream>>>(out, g_ffn, hnH, hnL);

        for (int c = 0; c < 4; ++c) {
            const size_t roff = (size_t)c * 1024 * D_MODEL;
            split_k<<<2048, blk, 0, stream>>>(W1, WfH, WfL, (int)(DF/4));
            gemm_hl<2><<<dim3(64, 8), blk, 0, stream>>>(
                hnH + roff, hnL + roff, WfH, WfL, nullptr,
                nullptr, GH, GL, 1024, D_FFN, D_MODEL);
            split_k<<<2048, blk, 0, stream>>>(W2, WfH, WfL, (int)(DF/4));
            gemm_hl<1><<<dim3(16, 8), blk, 0, stream>>>(
                GH, GL, WfH, WfL, out + roff,
                out + roff, nullptr, nullptr, 1024, D_MODEL, D_FFN);
        }
    }
    // else Tier 3: workspace too small -- launch nothing so the harness
    // reports a clean numeric failure (diagnostic) instead of a device fault.
}